// Round 13
// baseline (125.510 us; speedup 1.0000x reference)
//
#include <hip/hip_runtime.h>
#include <hip/hip_bf16.h>

typedef __bf16 b16x8 __attribute__((ext_vector_type(8)));
typedef unsigned short u16x8 __attribute__((ext_vector_type(8)));
typedef unsigned short u16x4 __attribute__((ext_vector_type(4)));
typedef unsigned int u32x4 __attribute__((ext_vector_type(4)));
typedef unsigned int u32x2 __attribute__((ext_vector_type(2)));
typedef float f32x4 __attribute__((ext_vector_type(4)));
typedef float f32x16 __attribute__((ext_vector_type(16)));

__device__ __forceinline__ unsigned short f2b(float f) {
  unsigned u = __builtin_bit_cast(unsigned, f);
  u += 0x7fff + ((u >> 16) & 1);   // round-to-nearest-even
  return (unsigned short)(u >> 16);
}

__device__ __forceinline__ b16x8 as_b(u16x8 v) { return __builtin_bit_cast(b16x8, v); }

__device__ __forceinline__ float fexp2(float x) {
#if __has_builtin(__builtin_amdgcn_exp2f)
  return __builtin_amdgcn_exp2f(x);
#else
  return exp2f(x);
#endif
}

// packed f32x2 -> bf16x2 (RNE), single instruction
__device__ __forceinline__ unsigned cvtpk(float lo, float hi) {
  unsigned r;
  asm("v_cvt_pk_bf16_f32 %0, %1, %2" : "=v"(r) : "v"(lo), "v"(hi));
  return r;
}

__device__ __forceinline__ void plswap(unsigned& a, unsigned& b) {
  asm volatile("v_permlane32_swap_b32 %0, %1" : "+v"(a), "+v"(b));
}

// P-fragment redistribution (round-2 derivation, numerically verified).
__device__ __forceinline__ b16x8 mkchunk(float p0, float p1, float p2, float p3,
                                         float p4, float p5, float p6, float p7) {
  unsigned a1 = cvtpk(p0, p1), b1 = cvtpk(p4, p5);
  unsigned a2 = cvtpk(p2, p3), b2 = cvtpk(p6, p7);
  plswap(a1, b1);
  plswap(a2, b2);
  u32x4 w = {a1, a2, b1, b2};
  return __builtin_bit_cast(b16x8, w);
}

#define AS1 __attribute__((address_space(1)))
#define AS3 __attribute__((address_space(3)))
__device__ __forceinline__ void gload_lds16(const void* g, void* l) {
  __builtin_amdgcn_global_load_lds((const AS1 void*)g, (AS3 void*)l, 16, 0, 0);
}

#define WAITV4() asm volatile("s_waitcnt vmcnt(4)" ::: "memory")
#define WAITV0() asm volatile("s_waitcnt vmcnt(0)" ::: "memory")
#define LGKM0()  asm volatile("s_waitcnt lgkmcnt(0)" ::: "memory")
#define BARRIER() asm volatile("s_barrier" ::: "memory")

// Global pre-swizzle convention: within each 64-elem chunk of a row, 16B slot
// s holds data of slot s ^ (row & 7). global_load_lds (linear) reproduces the
// swizzled LDS layout; ds_read applies idx ^= (row&7)<<3.

// ---------------------------------------------------------------------------
// convert: fp32 weights [1024][1024] -> bf16 pre-swizzled. grid (512, 4).
// (Activations q/k/v are converted in-register inside proj_kernel now.)
// ---------------------------------------------------------------------------
__global__ __launch_bounds__(256) void convert_kernel(
    const float* __restrict__ Wq, const float* __restrict__ Wk,
    const float* __restrict__ Wv, const float* __restrict__ Wo,
    unsigned short* __restrict__ wqb, unsigned short* __restrict__ wkb,
    unsigned short* __restrict__ wvb, unsigned short* __restrict__ wob) {
  const float* src; unsigned short* dst;
  switch (blockIdx.y) {
    case 0: src = Wq; dst = wqb; break;
    case 1: src = Wk; dst = wkb; break;
    case 2: src = Wv; dst = wvb; break;
    default: src = Wo; dst = wob; break;
  }
  const int row = blockIdx.x * 2 + (threadIdx.x >> 7);
  const int t = threadIdx.x & 127;
  const float* sp = src + (size_t)row * 1024 + t * 8;
  float4 f0 = *(const float4*)sp;
  float4 f1 = *(const float4*)(sp + 4);
  u16x8 h = { f2b(f0.x), f2b(f0.y), f2b(f0.z), f2b(f0.w),
              f2b(f1.x), f2b(f1.y), f2b(f1.z), f2b(f1.w) };
  const int swcol = ((t >> 3) << 6) | (((t & 7) ^ (row & 7)) << 3);
  *(u16x8*)(dst + (size_t)row * 1024 + swcol) = h;
}

// ---------------------------------------------------------------------------
// GEMM: C[M][1024] = A[M][1024] * W[1024][1024]^T + bias. BM=64, BN=128, BK=64.
// AFP32=1: A is raw fp32, staged via reg-load + cvt_pk + swizzled ds_write
// (fuses the old activation-convert pass). AFP32=0: A bf16 pre-swz, gload_lds.
// ---------------------------------------------------------------------------
template <int MODE, int AFP32, typename TOUT>
__device__ __forceinline__ void gemm_body(unsigned short* sA, unsigned short* sB,
                                          const void* __restrict__ Av,
                                          const unsigned short* __restrict__ Bm,
                                          const float* __restrict__ bias,
                                          TOUT* __restrict__ C,
                                          int bm, int bn) {
  const int tid = threadIdx.x;
  const int l = tid & 63, w = tid >> 6;
  const int wm = w >> 1, wn = w & 1;
  const int lr = l & 15, lg = l >> 4;
  const int r8 = l >> 3, sl = l & 7;

  f32x4 acc[2][4] = {};

  for (int k0 = 0; k0 < 1024; k0 += 64) {
    if constexpr (AFP32) {
      // reg-staged fp32 -> bf16: thread t covers row tid>>2, 16-col segment
      const int arow = tid >> 2, aseg = (tid & 3) * 16;
      const float* ap = (const float*)Av + (size_t)(bm + arow) * 1024 + k0 + aseg;
      float4 f0 = *(const float4*)(ap);
      float4 f1 = *(const float4*)(ap + 4);
      float4 f2 = *(const float4*)(ap + 8);
      float4 f3 = *(const float4*)(ap + 12);
      u32x4 h0 = { cvtpk(f0.x, f0.y), cvtpk(f0.z, f0.w),
                   cvtpk(f1.x, f1.y), cvtpk(f1.z, f1.w) };
      u32x4 h1 = { cvtpk(f2.x, f2.y), cvtpk(f2.z, f2.w),
                   cvtpk(f3.x, f3.y), cvtpk(f3.z, f3.w) };
      *(u32x4*)(&sA[(arow * 64 + aseg) ^ ((arow & 7) << 3)]) = h0;
      *(u32x4*)(&sA[(arow * 64 + aseg + 8) ^ ((arow & 7) << 3)]) = h1;
    } else {
#pragma unroll
      for (int i = 0; i < 2; ++i) {
        gload_lds16((const unsigned short*)Av + (size_t)(bm + i * 32 + w * 8 + r8) * 1024 + k0 + sl * 8,
                    &sA[i * 2048 + w * 512]);
      }
    }
#pragma unroll
    for (int i = 0; i < 4; ++i) {
      const int row = i * 32 + w * 8 + r8;
      gload_lds16(Bm + (size_t)(bn + row) * 1024 + k0 + sl * 8, &sB[i * 2048 + w * 512]);
    }
    __syncthreads();

    b16x8 af[2][2], bf[4][2];
#pragma unroll
    for (int mb = 0; mb < 2; ++mb)
#pragma unroll
      for (int kh = 0; kh < 2; ++kh) {
        const int r = wm * 32 + mb * 16 + lr;
        af[mb][kh] = as_b(*(const u16x8*)(&sA[(r * 64 + kh * 32 + lg * 8) ^ ((r & 7) << 3)]));
      }
#pragma unroll
    for (int nb = 0; nb < 4; ++nb)
#pragma unroll
      for (int kh = 0; kh < 2; ++kh) {
        const int r = wn * 64 + nb * 16 + lr;
        bf[nb][kh] = as_b(*(const u16x8*)(&sB[(r * 64 + kh * 32 + lg * 8) ^ ((r & 7) << 3)]));
      }
#pragma unroll
    for (int mb = 0; mb < 2; ++mb)
#pragma unroll
      for (int nb = 0; nb < 4; ++nb) {
        acc[mb][nb] = __builtin_amdgcn_mfma_f32_16x16x32_bf16(af[mb][0], bf[nb][0], acc[mb][nb], 0, 0, 0);
        acc[mb][nb] = __builtin_amdgcn_mfma_f32_16x16x32_bf16(af[mb][1], bf[nb][1], acc[mb][nb], 0, 0, 0);
      }
    __syncthreads();
  }

  const float qscale = 0.125f * 1.44269504f;
#pragma unroll
  for (int mb = 0; mb < 2; ++mb)
#pragma unroll
    for (int nb = 0; nb < 4; ++nb) {
      const int c = bn + wn * 64 + nb * 16 + lr;
      const float bv = bias[c];
      const int r0 = bm + wm * 32 + mb * 16 + lg * 4;
      if constexpr (MODE == 2) {
        const int hh = c >> 6, hd = c & 63;
        const int bb = r0 >> 11, t0 = r0 & 2047;
        u16x4 pk = { f2b(acc[mb][nb][0] + bv), f2b(acc[mb][nb][1] + bv),
                     f2b(acc[mb][nb][2] + bv), f2b(acc[mb][nb][3] + bv) };
        const int tsw = (t0 & ~63) | (((((t0 >> 3) & 7) ^ (hd & 7)) << 3)) | (t0 & 7);
        *(u16x4*)(&C[(((size_t)bb * 16 + hh) * 64 + hd) * 2048 + tsw]) = pk;
      } else {
#pragma unroll
        for (int i = 0; i < 4; ++i) {
          float val = acc[mb][nb][i] + bv;
          if constexpr (MODE == 1) val *= qscale;
          if constexpr (MODE == 3) {
            C[(size_t)(r0 + i) * 1024 + c] = val;
          } else {
            const int cc = (c & ~63) | (((((c >> 3) & 7) ^ ((r0 + i) & 7)) << 3)) | (c & 7);
            C[(size_t)(r0 + i) * 1024 + cc] = (TOUT)f2b(val);
          }
        }
      }
    }
}

// flat grid 1536 = bx*192 + bz*64 + by; 192 % 8 == 0 so the 8 bx-siblings of
// an A-panel (fixed by,bz) share id%8 -> same XCD -> A fetched once per panel.
__global__ __launch_bounds__(256) void proj_kernel(
    const float* __restrict__ q, const float* __restrict__ k, const float* __restrict__ v,
    const unsigned short* __restrict__ wqb, const float* __restrict__ bq,
    const unsigned short* __restrict__ wkb, const float* __restrict__ bk,
    const unsigned short* __restrict__ wvb, const float* __restrict__ bv,
    unsigned short* __restrict__ Qh, unsigned short* __restrict__ Kh,
    unsigned short* __restrict__ Vt) {
  __shared__ __align__(16) unsigned short sA[64 * 64];
  __shared__ __align__(16) unsigned short sB[128 * 64];
  const int id = blockIdx.x;
  const int bn = (id / 192) * 128;
  const int w_ = id % 192;
  const int bz = w_ / 64;
  const int bm = (w_ % 64) * 64;
  if (bz == 0)      gemm_body<1, 1, unsigned short>(sA, sB, q, wqb, bq, Qh, bm, bn);
  else if (bz == 1) gemm_body<0, 1, unsigned short>(sA, sB, k, wkb, bk, Kh, bm, bn);
  else              gemm_body<2, 1, unsigned short>(sA, sB, v, wvb, bv, Vt, bm, bn);
}

// flat grid 512 = bx*64 + by; 64 % 8 == 0 -> same-XCD A-panel sharing.
__global__ __launch_bounds__(256) void out_kernel(
    const unsigned short* __restrict__ X, const unsigned short* __restrict__ wob,
    const float* __restrict__ bo, float* __restrict__ out) {
  __shared__ __align__(16) unsigned short sA[64 * 64];
  __shared__ __align__(16) unsigned short sB[128 * 64];
  const int id = blockIdx.x;
  const int bn = (id / 64) * 128;
  const int bm = (id % 64) * 64;
  gemm_body<3, 0, float>(sA, sB, X, wob, bo, out, bm, bn);
}

// ---------------------------------------------------------------------------
// Flash attention — round-8 body (53.5 µs, VGPR 64, no spill), unchanged.
// The defer-max `if (__any)` branch is LOAD-BEARING for register allocation
// (rounds 10-11: removing it caused 143 MB scratch traffic).
// ---------------------------------------------------------------------------
__global__ __launch_bounds__(512, 4) void attn_kernel(
    const unsigned short* __restrict__ Qh, const unsigned short* __restrict__ Kh,
    const unsigned short* __restrict__ Vt, unsigned short* __restrict__ X) {
  __shared__ __align__(16) unsigned short sMem[8][4096];   // 64 KB

  const int tid = threadIdx.x;
  const int l = tid & 63, wq = tid >> 6;
  const int half = wq >> 2, w4 = wq & 3;
  const int lq = l & 31, lg = l >> 5;

  // XCD-aware bijective swizzle (512 blocks = 8 XCD x 64).
  const int id = blockIdx.x + (int)(gridDim.x * blockIdx.y);
  const int id2 = (id & 7) * 64 + (id >> 3);
  const int bx = id2 & 15, by = id2 >> 4;
  const int b = by >> 4, h = by & 15;
  const int q0 = bx * 128 + w4 * 32;
  const int kvbase = half * 1024;

  const size_t baseQK = (size_t)b * 2048 * 1024 + (size_t)h * 64;
  const size_t baseV  = ((size_t)(b * 16 + h)) * 64 * 2048;

  unsigned short* sK0 = &sMem[half * 4 + 0][0];
  unsigned short* sK1 = &sMem[half * 4 + 1][0];
  unsigned short* sV0 = &sMem[half * 4 + 2][0];
  unsigned short* sV1 = &sMem[half * 4 + 3][0];

  const int rk = lq & 7;
  b16x8 qf0, qf1, qf2, qf3;
  {
    const unsigned short* qp = Qh + baseQK + (size_t)(q0 + lq) * 1024;
    qf0 = as_b(*(const u16x8*)(qp + (((0 + lg) ^ rk) << 3)));
    qf1 = as_b(*(const u16x8*)(qp + (((2 + lg) ^ rk) << 3)));
    qf2 = as_b(*(const u16x8*)(qp + (((4 + lg) ^ rk) << 3)));
    qf3 = as_b(*(const u16x8*)(qp + (((6 + lg) ^ rk) << 3)));
  }

  const int r8 = l >> 3, sl = l & 7;

  auto stageKV = [&](unsigned short* dK, unsigned short* dV, int kv0) {
#pragma unroll
    for (int i = 0; i < 2; ++i) {
      const int rowb = 16 * w4 + 8 * i;
      gload_lds16(Kh + baseQK + (size_t)(kv0 + rowb + r8) * 1024 + sl * 8, dK + rowb * 64);
      gload_lds16(Vt + baseV + (size_t)(rowb + r8) * 2048 + kv0 + sl * 8, dV + rowb * 64);
    }
  };

  float m_run = 0.f, l_run = 0.f;   // m relative; defer-max keeps it stale
  f32x16 Oa = {}, Ob = {};
  const int sw = (lq & 7) << 3;

  auto body = [&](const unsigned short* K_, const unsigned short* V_) {
    // S = QK^T - m_run  (fold the softmax shift into the MFMA C-init)
    f32x16 s0, s1;
#pragma unroll
    for (int j = 0; j < 16; ++j) { s0[j] = -m_run; s1[j] = -m_run; }
    __builtin_amdgcn_s_setprio(1);
#pragma unroll
    for (int c = 0; c < 4; ++c) {
      const int hd8 = c * 16 + 8 * lg;
      b16x8 kf0 = as_b(*(const u16x8*)(&K_[lq * 64 + (hd8 ^ sw)]));
      b16x8 kf1 = as_b(*(const u16x8*)(&K_[(32 + lq) * 64 + (hd8 ^ sw)]));
      b16x8 qf = (c == 0) ? qf0 : (c == 1) ? qf1 : (c == 2) ? qf2 : qf3;
      s0 = __builtin_amdgcn_mfma_f32_32x32x16_bf16(kf0, qf, s0, 0, 0, 0);
      s1 = __builtin_amdgcn_mfma_f32_32x32x16_bf16(kf1, qf, s1, 0, 0, 0);
    }
    __builtin_amdgcn_s_setprio(0);

    // tree max of (score - m_run)
    float a0 = fmaxf(fmaxf(s0[0], s0[1]), fmaxf(s0[2], s0[3]));
    float a1 = fmaxf(fmaxf(s0[4], s0[5]), fmaxf(s0[6], s0[7]));
    float a2 = fmaxf(fmaxf(s0[8], s0[9]), fmaxf(s0[10], s0[11]));
    float a3 = fmaxf(fmaxf(s0[12], s0[13]), fmaxf(s0[14], s0[15]));
    float a4 = fmaxf(fmaxf(s1[0], s1[1]), fmaxf(s1[2], s1[3]));
    float a5 = fmaxf(fmaxf(s1[4], s1[5]), fmaxf(s1[6], s1[7]));
    float a6 = fmaxf(fmaxf(s1[8], s1[9]), fmaxf(s1[10], s1[11]));
    float a7 = fmaxf(fmaxf(s1[12], s1[13]), fmaxf(s1[14], s1[15]));
    float mx = fmaxf(fmaxf(fmaxf(a0, a1), fmaxf(a2, a3)),
                     fmaxf(fmaxf(a4, a5), fmaxf(a6, a7)));
    mx = fmaxf(mx, __shfl_xor(mx, 32));

    // defer-max: only rescale when the shifted max exceeds 8 (exp2 domain)
    if (__any(mx > 8.0f)) {
      const float dm = fmaxf(mx, 0.f);
      const float al = fexp2(-dm);
      m_run += dm;
      l_run *= al;
#pragma unroll
      for (int j = 0; j < 16; ++j) {
        Oa[j] *= al; Ob[j] *= al; s0[j] -= dm; s1[j] -= dm;
      }
    }

#pragma unroll
    for (int j = 0; j < 16; ++j) s0[j] = fexp2(s0[j]);
#pragma unroll
    for (int j = 0; j < 16; ++j) s1[j] = fexp2(s1[j]);

    float r0 = ((s0[0] + s0[1]) + (s0[2] + s0[3])) + ((s0[4] + s0[5]) + (s0[6] + s0[7]));
    float r1 = ((s0[8] + s0[9]) + (s0[10] + s0[11])) + ((s0[12] + s0[13]) + (s0[14] + s0[15]));
    float r2 = ((s1[0] + s1[1]) + (s1[2] + s1[3])) + ((s1[4] + s1[5]) + (s1[6] + s1[7]));
    float r3 = ((s1[8] + s1[9]) + (s1[10] + s1[11])) + ((s1[12] + s1[13]) + (s1[14] + s1[15]));
    float rs = (r0 + r1) + (r2 + r3);
    rs += __shfl_xor(rs, 32);
    l_run += rs;

    b16x8 pb0 = mkchunk(s0[0], s0[1], s0[2], s0[3], s0[4], s0[5], s0[6], s0[7]);
    b16x8 pb1 = mkchunk(s0[8], s0[9], s0[10], s0[11], s0[12], s0[13], s0[14], s0[15]);
    b16x8 pb2 = mkchunk(s1[0], s1[1], s1[2], s1[3], s1[4], s1[5], s1[6], s1[7]);
    b16x8 pb3 = mkchunk(s1[8], s1[9], s1[10], s1[11], s1[12], s1[13], s1[14], s1[15]);

    __builtin_amdgcn_s_setprio(1);
#pragma unroll
    for (int c = 0; c < 4; ++c) {
      const int kv8 = c * 16 + 8 * lg;
      b16x8 vfa = as_b(*(const u16x8*)(&V_[lq * 64 + (kv8 ^ sw)]));
      b16x8 vfb = as_b(*(const u16x8*)(&V_[(32 + lq) * 64 + (kv8 ^ sw)]));
      b16x8 pb = (c == 0) ? pb0 : (c == 1) ? pb1 : (c == 2) ? pb2 : pb3;
      Oa = __builtin_amdgcn_mfma_f32_32x32x16_bf16(vfa, pb, Oa, 0, 0, 0);
      Ob = __builtin_amdgcn_mfma_f32_32x32x16_bf16(vfb, pb, Ob, 0, 0, 0);
    }
    __builtin_amdgcn_s_setprio(0);
  };

  // prologue: two tiles in flight
  stageKV(sK0, sV0, kvbase);
  stageKV(sK1, sV1, kvbase + 64);

#pragma unroll 1
  for (int tt = 0; tt < 16; tt += 2) {
    WAITV4();
    BARRIER();
    body(sK0, sV0);
    LGKM0();
    BARRIER();
    if (tt + 2 < 16) stageKV(sK0, sV0, kvbase + (tt + 2) * 64);

    if (tt + 3 < 16) { WAITV4(); } else { WAITV0(); }
    BARRIER();
    body(sK1, sV1);
    LGKM0();
    BARRIER();
    if (tt + 3 < 16) stageKV(sK1, sV1, kvbase + (tt + 3) * 64);
  }

  // merge the two kv-halves (LSE combine), then write X
  float* fb = (float*)&sMem[0][0];   // 34 x 256 floats, reuses K/V space
  const int mbase = w4 * 64 + l;
  if (half == 1) {
    fb[0 * 256 + mbase] = m_run;
    fb[1 * 256 + mbase] = l_run;
#pragma unroll
    for (int j = 0; j < 16; ++j) fb[(2 + j) * 256 + mbase] = Oa[j];
#pragma unroll
    for (int j = 0; j < 16; ++j) fb[(18 + j) * 256 + mbase] = Ob[j];
  }
  __syncthreads();
  if (half == 0) {
    const float m2 = fb[0 * 256 + mbase], l2 = fb[1 * 256 + mbase];
    const float mM = fmaxf(m_run, m2);
    const float c1 = fexp2(m_run - mM), c2 = fexp2(m2 - mM);
    const float inv = 1.0f / (l_run * c1 + l2 * c2);
    const float ia = c1 * inv, ib = c2 * inv;
#pragma unroll
    for (int j = 0; j < 16; ++j) {
      Oa[j] = Oa[j] * ia + fb[(2 + j) * 256 + mbase] * ib;
      Ob[j] = Ob[j] * ia + fb[(18 + j) * 256 + mbase] * ib;
    }
    unsigned short* xp = X + baseQK + (size_t)(q0 + lq) * 1024;
#pragma unroll
    for (int g = 0; g < 4; ++g) {
      u32x2 wa = { cvtpk(Oa[4 * g + 0], Oa[4 * g + 1]),
                   cvtpk(Oa[4 * g + 2], Oa[4 * g + 3]) };
      *(u32x2*)(xp + ((g ^ rk) << 3) + 4 * lg) = wa;
      u32x2 wb = { cvtpk(Ob[4 * g + 0], Ob[4 * g + 1]),
                   cvtpk(Ob[4 * g + 2], Ob[4 * g + 3]) };
      *(u32x2*)(xp + (((4 + g) ^ rk) << 3) + 4 * lg) = wb;
    }
  }
}

extern "C" void kernel_launch(void* const* d_in, const int* in_sizes, int n_in,
                              void* d_out, int out_size, void* d_ws, size_t ws_size,
                              hipStream_t stream) {
  const float* q  = (const float*)d_in[0];
  const float* k  = (const float*)d_in[1];
  const float* v  = (const float*)d_in[2];
  const float* Wq = (const float*)d_in[3];
  const float* bq = (const float*)d_in[4];
  const float* Wk = (const float*)d_in[5];
  const float* bk = (const float*)d_in[6];
  const float* Wv = (const float*)d_in[7];
  const float* bv = (const float*)d_in[8];
  const float* Wo = (const float*)d_in[9];
  const float* bo = (const float*)d_in[10];

  unsigned short* ws = (unsigned short*)d_ws;
  const size_t M1 = (size_t)1024 * 1024;
  unsigned short* wqb = ws + 12 * M1;
  unsigned short* wkb = ws + 13 * M1;
  unsigned short* wvb = ws + 14 * M1;
  unsigned short* wob = ws + 15 * M1;
  unsigned short* Qh  = ws + 16 * M1;
  unsigned short* Kh  = ws + 20 * M1;
  unsigned short* Vt  = ws + 24 * M1;
  unsigned short* X   = ws;              // first 4M elems (old qb slot)

  dim3 blk(256);
  convert_kernel<<<dim3(512, 4), blk, 0, stream>>>(Wq, Wk, Wv, Wo, wqb, wkb, wvb, wob);
  proj_kernel<<<dim3(1536), blk, 0, stream>>>(q, k, v, wqb, bq, wkb, bk, wvb, bv,
                                              Qh, Kh, Vt);
  attn_kernel<<<dim3(16, 32), dim3(512), 0, stream>>>(Qh, Kh, Vt, X);
  out_kernel<<<dim3(512), blk, 0, stream>>>(X, wob, bo, (float*)d_out);
}

// Round 14
// 120.884 us; speedup vs baseline: 1.0383x; 1.0383x over previous
//
#include <hip/hip_runtime.h>
#include <hip/hip_bf16.h>

typedef __bf16 b16x8 __attribute__((ext_vector_type(8)));
typedef unsigned short u16x8 __attribute__((ext_vector_type(8)));
typedef unsigned short u16x4 __attribute__((ext_vector_type(4)));
typedef unsigned int u32x4 __attribute__((ext_vector_type(4)));
typedef unsigned int u32x2 __attribute__((ext_vector_type(2)));
typedef float f32x4 __attribute__((ext_vector_type(4)));
typedef float f32x16 __attribute__((ext_vector_type(16)));

__device__ __forceinline__ unsigned short f2b(float f) {
  unsigned u = __builtin_bit_cast(unsigned, f);
  u += 0x7fff + ((u >> 16) & 1);   // round-to-nearest-even
  return (unsigned short)(u >> 16);
}

__device__ __forceinline__ b16x8 as_b(u16x8 v) { return __builtin_bit_cast(b16x8, v); }

__device__ __forceinline__ float fexp2(float x) {
#if __has_builtin(__builtin_amdgcn_exp2f)
  return __builtin_amdgcn_exp2f(x);
#else
  return exp2f(x);
#endif
}

// packed f32x2 -> bf16x2 (RNE), single instruction
__device__ __forceinline__ unsigned cvtpk(float lo, float hi) {
  unsigned r;
  asm("v_cvt_pk_bf16_f32 %0, %1, %2" : "=v"(r) : "v"(lo), "v"(hi));
  return r;
}

__device__ __forceinline__ void plswap(unsigned& a, unsigned& b) {
  asm volatile("v_permlane32_swap_b32 %0, %1" : "+v"(a), "+v"(b));
}

// P-fragment redistribution (round-2 derivation, numerically verified).
__device__ __forceinline__ b16x8 mkchunk(float p0, float p1, float p2, float p3,
                                         float p4, float p5, float p6, float p7) {
  unsigned a1 = cvtpk(p0, p1), b1 = cvtpk(p4, p5);
  unsigned a2 = cvtpk(p2, p3), b2 = cvtpk(p6, p7);
  plswap(a1, b1);
  plswap(a2, b2);
  u32x4 w = {a1, a2, b1, b2};
  return __builtin_bit_cast(b16x8, w);
}

#define AS1 __attribute__((address_space(1)))
#define AS3 __attribute__((address_space(3)))
__device__ __forceinline__ void gload_lds16(const void* g, void* l) {
  __builtin_amdgcn_global_load_lds((const AS1 void*)g, (AS3 void*)l, 16, 0, 0);
}

#define WAITV4() asm volatile("s_waitcnt vmcnt(4)" ::: "memory")
#define WAITV0() asm volatile("s_waitcnt vmcnt(0)" ::: "memory")
#define LGKM0()  asm volatile("s_waitcnt lgkmcnt(0)" ::: "memory")
#define BARRIER() asm volatile("s_barrier" ::: "memory")

// Global pre-swizzle convention: within each 64-elem chunk of a row, 16B slot
// s holds data of slot s ^ (row & 7). global_load_lds (linear) reproduces the
// swizzled LDS layout; ds_read applies idx ^= (row&7)<<3.

// ---------------------------------------------------------------------------
// convert: fp32 weights [1024][1024] -> bf16 pre-swizzled. grid (512, 4).
// ---------------------------------------------------------------------------
__global__ __launch_bounds__(256) void convert_kernel(
    const float* __restrict__ Wq, const float* __restrict__ Wk,
    const float* __restrict__ Wv, const float* __restrict__ Wo,
    unsigned short* __restrict__ wqb, unsigned short* __restrict__ wkb,
    unsigned short* __restrict__ wvb, unsigned short* __restrict__ wob) {
  const float* src; unsigned short* dst;
  switch (blockIdx.y) {
    case 0: src = Wq; dst = wqb; break;
    case 1: src = Wk; dst = wkb; break;
    case 2: src = Wv; dst = wvb; break;
    default: src = Wo; dst = wob; break;
  }
  const int row = blockIdx.x * 2 + (threadIdx.x >> 7);
  const int t = threadIdx.x & 127;
  const float* sp = src + (size_t)row * 1024 + t * 8;
  float4 f0 = *(const float4*)sp;
  float4 f1 = *(const float4*)(sp + 4);
  u16x8 h = { f2b(f0.x), f2b(f0.y), f2b(f0.z), f2b(f0.w),
              f2b(f1.x), f2b(f1.y), f2b(f1.z), f2b(f1.w) };
  const int swcol = ((t >> 3) << 6) | (((t & 7) ^ (row & 7)) << 3);
  *(u16x8*)(dst + (size_t)row * 1024 + swcol) = h;
}

// ---------------------------------------------------------------------------
// GEMM: C[M][1024] = A[M][1024] * W[1024][1024]^T + bias. BM=64, BN=128, BK=64.
// AFP32=1: A is raw fp32, staged via reg-load + cvt_pk + swizzled ds_write
// (fuses the activation-convert pass). AFP32=0: A bf16 pre-swz, gload_lds.
// ---------------------------------------------------------------------------
template <int MODE, int AFP32, typename TOUT>
__device__ __forceinline__ void gemm_body(unsigned short* sA, unsigned short* sB,
                                          const void* __restrict__ Av,
                                          const unsigned short* __restrict__ Bm,
                                          const float* __restrict__ bias,
                                          TOUT* __restrict__ C,
                                          int bm, int bn) {
  const int tid = threadIdx.x;
  const int l = tid & 63, w = tid >> 6;
  const int wm = w >> 1, wn = w & 1;
  const int lr = l & 15, lg = l >> 4;
  const int r8 = l >> 3, sl = l & 7;

  f32x4 acc[2][4] = {};

  for (int k0 = 0; k0 < 1024; k0 += 64) {
    if constexpr (AFP32) {
      // reg-staged fp32 -> bf16: thread t covers row tid>>2, 16-col segment
      const int arow = tid >> 2, aseg = (tid & 3) * 16;
      const float* ap = (const float*)Av + (size_t)(bm + arow) * 1024 + k0 + aseg;
      float4 f0 = *(const float4*)(ap);
      float4 f1 = *(const float4*)(ap + 4);
      float4 f2 = *(const float4*)(ap + 8);
      float4 f3 = *(const float4*)(ap + 12);
      u32x4 h0 = { cvtpk(f0.x, f0.y), cvtpk(f0.z, f0.w),
                   cvtpk(f1.x, f1.y), cvtpk(f1.z, f1.w) };
      u32x4 h1 = { cvtpk(f2.x, f2.y), cvtpk(f2.z, f2.w),
                   cvtpk(f3.x, f3.y), cvtpk(f3.z, f3.w) };
      *(u32x4*)(&sA[(arow * 64 + aseg) ^ ((arow & 7) << 3)]) = h0;
      *(u32x4*)(&sA[(arow * 64 + aseg + 8) ^ ((arow & 7) << 3)]) = h1;
    } else {
#pragma unroll
      for (int i = 0; i < 2; ++i) {
        gload_lds16((const unsigned short*)Av + (size_t)(bm + i * 32 + w * 8 + r8) * 1024 + k0 + sl * 8,
                    &sA[i * 2048 + w * 512]);
      }
    }
#pragma unroll
    for (int i = 0; i < 4; ++i) {
      const int row = i * 32 + w * 8 + r8;
      gload_lds16(Bm + (size_t)(bn + row) * 1024 + k0 + sl * 8, &sB[i * 2048 + w * 512]);
    }
    __syncthreads();

    b16x8 af[2][2], bf[4][2];
#pragma unroll
    for (int mb = 0; mb < 2; ++mb)
#pragma unroll
      for (int kh = 0; kh < 2; ++kh) {
        const int r = wm * 32 + mb * 16 + lr;
        af[mb][kh] = as_b(*(const u16x8*)(&sA[(r * 64 + kh * 32 + lg * 8) ^ ((r & 7) << 3)]));
      }
#pragma unroll
    for (int nb = 0; nb < 4; ++nb)
#pragma unroll
      for (int kh = 0; kh < 2; ++kh) {
        const int r = wn * 64 + nb * 16 + lr;
        bf[nb][kh] = as_b(*(const u16x8*)(&sB[(r * 64 + kh * 32 + lg * 8) ^ ((r & 7) << 3)]));
      }
#pragma unroll
    for (int mb = 0; mb < 2; ++mb)
#pragma unroll
      for (int nb = 0; nb < 4; ++nb) {
        acc[mb][nb] = __builtin_amdgcn_mfma_f32_16x16x32_bf16(af[mb][0], bf[nb][0], acc[mb][nb], 0, 0, 0);
        acc[mb][nb] = __builtin_amdgcn_mfma_f32_16x16x32_bf16(af[mb][1], bf[nb][1], acc[mb][nb], 0, 0, 0);
      }
    __syncthreads();
  }

  const float qscale = 0.125f * 1.44269504f;
#pragma unroll
  for (int mb = 0; mb < 2; ++mb)
#pragma unroll
    for (int nb = 0; nb < 4; ++nb) {
      const int c = bn + wn * 64 + nb * 16 + lr;
      const float bv = bias[c];
      const int r0 = bm + wm * 32 + mb * 16 + lg * 4;
      if constexpr (MODE == 2) {
        const int hh = c >> 6, hd = c & 63;
        const int bb = r0 >> 11, t0 = r0 & 2047;
        u16x4 pk = { f2b(acc[mb][nb][0] + bv), f2b(acc[mb][nb][1] + bv),
                     f2b(acc[mb][nb][2] + bv), f2b(acc[mb][nb][3] + bv) };
        const int tsw = (t0 & ~63) | (((((t0 >> 3) & 7) ^ (hd & 7)) << 3)) | (t0 & 7);
        *(u16x4*)(&C[(((size_t)bb * 16 + hh) * 64 + hd) * 2048 + tsw]) = pk;
      } else {
#pragma unroll
        for (int i = 0; i < 4; ++i) {
          float val = acc[mb][nb][i] + bv;
          if constexpr (MODE == 1) val *= qscale;
          if constexpr (MODE == 3) {
            C[(size_t)(r0 + i) * 1024 + c] = val;
          } else {
            const int cc = (c & ~63) | (((((c >> 3) & 7) ^ ((r0 + i) & 7)) << 3)) | (c & 7);
            C[(size_t)(r0 + i) * 1024 + cc] = (TOUT)f2b(val);
          }
        }
      }
    }
}

// flat grid 1536 = g*64 + bx*8 + p, panel = g*8 + p.
// The 8 bx-siblings sharing an A-panel span ids base..base+56, all same id%8
// -> SAME XCD and TEMPORALLY ADJACENT -> A-panel fetched once into L2.
// (Round-13 mapping had siblings 192 apart -> evicted between uses.)
__global__ __launch_bounds__(256) void proj_kernel(
    const float* __restrict__ q, const float* __restrict__ k, const float* __restrict__ v,
    const unsigned short* __restrict__ wqb, const float* __restrict__ bq,
    const unsigned short* __restrict__ wkb, const float* __restrict__ bk,
    const unsigned short* __restrict__ wvb, const float* __restrict__ bv,
    unsigned short* __restrict__ Qh, unsigned short* __restrict__ Kh,
    unsigned short* __restrict__ Vt) {
  __shared__ __align__(16) unsigned short sA[64 * 64];
  __shared__ __align__(16) unsigned short sB[128 * 64];
  const int id = blockIdx.x;
  const int g = id >> 6, r = id & 63;
  const int bn = (r >> 3) * 128;
  const int panel = g * 8 + (r & 7);
  const int bz = panel >> 6;
  const int bm = (panel & 63) * 64;
  if (bz == 0)      gemm_body<1, 1, unsigned short>(sA, sB, q, wqb, bq, Qh, bm, bn);
  else if (bz == 1) gemm_body<0, 1, unsigned short>(sA, sB, k, wkb, bk, Kh, bm, bn);
  else              gemm_body<2, 1, unsigned short>(sA, sB, v, wvb, bv, Vt, bm, bn);
}

// flat grid 512 = g*64 + bx*8 + p, panel(by) = g*8 + p. Same sibling locality.
__global__ __launch_bounds__(256) void out_kernel(
    const unsigned short* __restrict__ X, const unsigned short* __restrict__ wob,
    const float* __restrict__ bo, float* __restrict__ out) {
  __shared__ __align__(16) unsigned short sA[64 * 64];
  __shared__ __align__(16) unsigned short sB[128 * 64];
  const int id = blockIdx.x;
  const int g = id >> 6, r = id & 63;
  const int bn = (r >> 3) * 128;
  const int bm = (g * 8 + (r & 7)) * 64;
  gemm_body<3, 0, float>(sA, sB, X, wob, bo, out, bm, bn);
}

// ---------------------------------------------------------------------------
// Flash attention — round-8 body (53.5 µs, VGPR 64, no spill), unchanged.
// The defer-max `if (__any)` branch is LOAD-BEARING for register allocation
// (rounds 10-11: removing it caused 143 MB scratch traffic).
// ---------------------------------------------------------------------------
__global__ __launch_bounds__(512, 4) void attn_kernel(
    const unsigned short* __restrict__ Qh, const unsigned short* __restrict__ Kh,
    const unsigned short* __restrict__ Vt, unsigned short* __restrict__ X) {
  __shared__ __align__(16) unsigned short sMem[8][4096];   // 64 KB

  const int tid = threadIdx.x;
  const int l = tid & 63, wq = tid >> 6;
  const int half = wq >> 2, w4 = wq & 3;
  const int lq = l & 31, lg = l >> 5;

  // XCD-aware bijective swizzle (512 blocks = 8 XCD x 64).
  const int id = blockIdx.x + (int)(gridDim.x * blockIdx.y);
  const int id2 = (id & 7) * 64 + (id >> 3);
  const int bx = id2 & 15, by = id2 >> 4;
  const int b = by >> 4, h = by & 15;
  const int q0 = bx * 128 + w4 * 32;
  const int kvbase = half * 1024;

  const size_t baseQK = (size_t)b * 2048 * 1024 + (size_t)h * 64;
  const size_t baseV  = ((size_t)(b * 16 + h)) * 64 * 2048;

  unsigned short* sK0 = &sMem[half * 4 + 0][0];
  unsigned short* sK1 = &sMem[half * 4 + 1][0];
  unsigned short* sV0 = &sMem[half * 4 + 2][0];
  unsigned short* sV1 = &sMem[half * 4 + 3][0];

  const int rk = lq & 7;
  b16x8 qf0, qf1, qf2, qf3;
  {
    const unsigned short* qp = Qh + baseQK + (size_t)(q0 + lq) * 1024;
    qf0 = as_b(*(const u16x8*)(qp + (((0 + lg) ^ rk) << 3)));
    qf1 = as_b(*(const u16x8*)(qp + (((2 + lg) ^ rk) << 3)));
    qf2 = as_b(*(const u16x8*)(qp + (((4 + lg) ^ rk) << 3)));
    qf3 = as_b(*(const u16x8*)(qp + (((6 + lg) ^ rk) << 3)));
  }

  const int r8 = l >> 3, sl = l & 7;

  auto stageKV = [&](unsigned short* dK, unsigned short* dV, int kv0) {
#pragma unroll
    for (int i = 0; i < 2; ++i) {
      const int rowb = 16 * w4 + 8 * i;
      gload_lds16(Kh + baseQK + (size_t)(kv0 + rowb + r8) * 1024 + sl * 8, dK + rowb * 64);
      gload_lds16(Vt + baseV + (size_t)(rowb + r8) * 2048 + kv0 + sl * 8, dV + rowb * 64);
    }
  };

  float m_run = 0.f, l_run = 0.f;   // m relative; defer-max keeps it stale
  f32x16 Oa = {}, Ob = {};
  const int sw = (lq & 7) << 3;

  auto body = [&](const unsigned short* K_, const unsigned short* V_) {
    // S = QK^T - m_run  (fold the softmax shift into the MFMA C-init)
    f32x16 s0, s1;
#pragma unroll
    for (int j = 0; j < 16; ++j) { s0[j] = -m_run; s1[j] = -m_run; }
    __builtin_amdgcn_s_setprio(1);
#pragma unroll
    for (int c = 0; c < 4; ++c) {
      const int hd8 = c * 16 + 8 * lg;
      b16x8 kf0 = as_b(*(const u16x8*)(&K_[lq * 64 + (hd8 ^ sw)]));
      b16x8 kf1 = as_b(*(const u16x8*)(&K_[(32 + lq) * 64 + (hd8 ^ sw)]));
      b16x8 qf = (c == 0) ? qf0 : (c == 1) ? qf1 : (c == 2) ? qf2 : qf3;
      s0 = __builtin_amdgcn_mfma_f32_32x32x16_bf16(kf0, qf, s0, 0, 0, 0);
      s1 = __builtin_amdgcn_mfma_f32_32x32x16_bf16(kf1, qf, s1, 0, 0, 0);
    }
    __builtin_amdgcn_s_setprio(0);

    // tree max of (score - m_run)
    float a0 = fmaxf(fmaxf(s0[0], s0[1]), fmaxf(s0[2], s0[3]));
    float a1 = fmaxf(fmaxf(s0[4], s0[5]), fmaxf(s0[6], s0[7]));
    float a2 = fmaxf(fmaxf(s0[8], s0[9]), fmaxf(s0[10], s0[11]));
    float a3 = fmaxf(fmaxf(s0[12], s0[13]), fmaxf(s0[14], s0[15]));
    float a4 = fmaxf(fmaxf(s1[0], s1[1]), fmaxf(s1[2], s1[3]));
    float a5 = fmaxf(fmaxf(s1[4], s1[5]), fmaxf(s1[6], s1[7]));
    float a6 = fmaxf(fmaxf(s1[8], s1[9]), fmaxf(s1[10], s1[11]));
    float a7 = fmaxf(fmaxf(s1[12], s1[13]), fmaxf(s1[14], s1[15]));
    float mx = fmaxf(fmaxf(fmaxf(a0, a1), fmaxf(a2, a3)),
                     fmaxf(fmaxf(a4, a5), fmaxf(a6, a7)));
    mx = fmaxf(mx, __shfl_xor(mx, 32));

    // defer-max: only rescale when the shifted max exceeds 8 (exp2 domain)
    if (__any(mx > 8.0f)) {
      const float dm = fmaxf(mx, 0.f);
      const float al = fexp2(-dm);
      m_run += dm;
      l_run *= al;
#pragma unroll
      for (int j = 0; j < 16; ++j) {
        Oa[j] *= al; Ob[j] *= al; s0[j] -= dm; s1[j] -= dm;
      }
    }

#pragma unroll
    for (int j = 0; j < 16; ++j) s0[j] = fexp2(s0[j]);
#pragma unroll
    for (int j = 0; j < 16; ++j) s1[j] = fexp2(s1[j]);

    float r0 = ((s0[0] + s0[1]) + (s0[2] + s0[3])) + ((s0[4] + s0[5]) + (s0[6] + s0[7]));
    float r1 = ((s0[8] + s0[9]) + (s0[10] + s0[11])) + ((s0[12] + s0[13]) + (s0[14] + s0[15]));
    float r2 = ((s1[0] + s1[1]) + (s1[2] + s1[3])) + ((s1[4] + s1[5]) + (s1[6] + s1[7]));
    float r3 = ((s1[8] + s1[9]) + (s1[10] + s1[11])) + ((s1[12] + s1[13]) + (s1[14] + s1[15]));
    float rs = (r0 + r1) + (r2 + r3);
    rs += __shfl_xor(rs, 32);
    l_run += rs;

    b16x8 pb0 = mkchunk(s0[0], s0[1], s0[2], s0[3], s0[4], s0[5], s0[6], s0[7]);
    b16x8 pb1 = mkchunk(s0[8], s0[9], s0[10], s0[11], s0[12], s0[13], s0[14], s0[15]);
    b16x8 pb2 = mkchunk(s1[0], s1[1], s1[2], s1[3], s1[4], s1[5], s1[6], s1[7]);
    b16x8 pb3 = mkchunk(s1[8], s1[9], s1[10], s1[11], s1[12], s1[13], s1[14], s1[15]);

    __builtin_amdgcn_s_setprio(1);
#pragma unroll
    for (int c = 0; c < 4; ++c) {
      const int kv8 = c * 16 + 8 * lg;
      b16x8 vfa = as_b(*(const u16x8*)(&V_[lq * 64 + (kv8 ^ sw)]));
      b16x8 vfb = as_b(*(const u16x8*)(&V_[(32 + lq) * 64 + (kv8 ^ sw)]));
      b16x8 pb = (c == 0) ? pb0 : (c == 1) ? pb1 : (c == 2) ? pb2 : pb3;
      Oa = __builtin_amdgcn_mfma_f32_32x32x16_bf16(vfa, pb, Oa, 0, 0, 0);
      Ob = __builtin_amdgcn_mfma_f32_32x32x16_bf16(vfb, pb, Ob, 0, 0, 0);
    }
    __builtin_amdgcn_s_setprio(0);
  };

  // prologue: two tiles in flight
  stageKV(sK0, sV0, kvbase);
  stageKV(sK1, sV1, kvbase + 64);

#pragma unroll 1
  for (int tt = 0; tt < 16; tt += 2) {
    WAITV4();
    BARRIER();
    body(sK0, sV0);
    LGKM0();
    BARRIER();
    if (tt + 2 < 16) stageKV(sK0, sV0, kvbase + (tt + 2) * 64);

    if (tt + 3 < 16) { WAITV4(); } else { WAITV0(); }
    BARRIER();
    body(sK1, sV1);
    LGKM0();
    BARRIER();
    if (tt + 3 < 16) stageKV(sK1, sV1, kvbase + (tt + 3) * 64);
  }

  // merge the two kv-halves (LSE combine), then write X
  float* fb = (float*)&sMem[0][0];   // 34 x 256 floats, reuses K/V space
  const int mbase = w4 * 64 + l;
  if (half == 1) {
    fb[0 * 256 + mbase] = m_run;
    fb[1 * 256 + mbase] = l_run;
#pragma unroll
    for (int j = 0; j < 16; ++j) fb[(2 + j) * 256 + mbase] = Oa[j];
#pragma unroll
    for (int j = 0; j < 16; ++j) fb[(18 + j) * 256 + mbase] = Ob[j];
  }
  __syncthreads();
  if (half == 0) {
    const float m2 = fb[0 * 256 + mbase], l2 = fb[1 * 256 + mbase];
    const float mM = fmaxf(m_run, m2);
    const float c1 = fexp2(m_run - mM), c2 = fexp2(m2 - mM);
    const float inv = 1.0f / (l_run * c1 + l2 * c2);
    const float ia = c1 * inv, ib = c2 * inv;
#pragma unroll
    for (int j = 0; j < 16; ++j) {
      Oa[j] = Oa[j] * ia + fb[(2 + j) * 256 + mbase] * ib;
      Ob[j] = Ob[j] * ia + fb[(18 + j) * 256 + mbase] * ib;
    }
    unsigned short* xp = X + baseQK + (size_t)(q0 + lq) * 1024;
#pragma unroll
    for (int g = 0; g < 4; ++g) {
      u32x2 wa = { cvtpk(Oa[4 * g + 0], Oa[4 * g + 1]),
                   cvtpk(Oa[4 * g + 2], Oa[4 * g + 3]) };
      *(u32x2*)(xp + ((g ^ rk) << 3) + 4 * lg) = wa;
      u32x2 wb = { cvtpk(Ob[4 * g + 0], Ob[4 * g + 1]),
                   cvtpk(Ob[4 * g + 2], Ob[4 * g + 3]) };
      *(u32x2*)(xp + (((4 + g) ^ rk) << 3) + 4 * lg) = wb;
    }
  }
}

extern "C" void kernel_launch(void* const* d_in, const int* in_sizes, int n_in,
                              void* d_out, int out_size, void* d_ws, size_t ws_size,
                              hipStream_t stream) {
  const float* q  = (const float*)d_in[0];
  const float* k  = (const float*)d_in[1];
  const float* v  = (const float*)d_in[2];
  const float* Wq = (const float*)d_in[3];
  const float* bq = (const float*)d_in[4];
  const float* Wk = (const float*)d_in[5];
  const float* bk = (const float*)d_in[6];
  const float* Wv = (const float*)d_in[7];
  const float* bv = (const float*)d_in[8];
  const float* Wo = (const float*)d_in[9];
  const float* bo = (const float*)d_in[10];

  unsigned short* ws = (unsigned short*)d_ws;
  const size_t M1 = (size_t)1024 * 1024;
  unsigned short* wqb = ws + 12 * M1;
  unsigned short* wkb = ws + 13 * M1;
  unsigned short* wvb = ws + 14 * M1;
  unsigned short* wob = ws + 15 * M1;
  unsigned short* Qh  = ws + 16 * M1;
  unsigned short* Kh  = ws + 20 * M1;
  unsigned short* Vt  = ws + 24 * M1;
  unsigned short* X   = ws;              // first 4M elems

  dim3 blk(256);
  convert_kernel<<<dim3(512, 4), blk, 0, stream>>>(Wq, Wk, Wv, Wo, wqb, wkb, wvb, wob);
  proj_kernel<<<dim3(1536), blk, 0, stream>>>(q, k, v, wqb, bq, wkb, bk, wvb, bv,
                                              Qh, Kh, Vt);
  attn_kernel<<<dim3(16, 32), dim3(512), 0, stream>>>(Qh, Kh, Vt, X);
  out_kernel<<<dim3(512), blk, 0, stream>>>(X, wob, bo, (float*)d_out);
}

// Round 15
// 117.170 us; speedup vs baseline: 1.0712x; 1.0317x over previous
//
#include <hip/hip_runtime.h>
#include <hip/hip_bf16.h>

typedef __bf16 b16x8 __attribute__((ext_vector_type(8)));
typedef unsigned short u16x8 __attribute__((ext_vector_type(8)));
typedef unsigned short u16x4 __attribute__((ext_vector_type(4)));
typedef unsigned int u32x4 __attribute__((ext_vector_type(4)));
typedef unsigned int u32x2 __attribute__((ext_vector_type(2)));
typedef float f32x4 __attribute__((ext_vector_type(4)));
typedef float f32x16 __attribute__((ext_vector_type(16)));

__device__ __forceinline__ unsigned short f2b(float f) {
  unsigned u = __builtin_bit_cast(unsigned, f);
  u += 0x7fff + ((u >> 16) & 1);   // round-to-nearest-even
  return (unsigned short)(u >> 16);
}

__device__ __forceinline__ b16x8 as_b(u16x8 v) { return __builtin_bit_cast(b16x8, v); }

__device__ __forceinline__ float fexp2(float x) {
#if __has_builtin(__builtin_amdgcn_exp2f)
  return __builtin_amdgcn_exp2f(x);
#else
  return exp2f(x);
#endif
}

// packed f32x2 -> bf16x2 (RNE), single instruction
__device__ __forceinline__ unsigned cvtpk(float lo, float hi) {
  unsigned r;
  asm("v_cvt_pk_bf16_f32 %0, %1, %2" : "=v"(r) : "v"(lo), "v"(hi));
  return r;
}

__device__ __forceinline__ void plswap(unsigned& a, unsigned& b) {
  asm volatile("v_permlane32_swap_b32 %0, %1" : "+v"(a), "+v"(b));
}

// P-fragment redistribution (round-2 derivation, numerically verified).
__device__ __forceinline__ b16x8 mkchunk(float p0, float p1, float p2, float p3,
                                         float p4, float p5, float p6, float p7) {
  unsigned a1 = cvtpk(p0, p1), b1 = cvtpk(p4, p5);
  unsigned a2 = cvtpk(p2, p3), b2 = cvtpk(p6, p7);
  plswap(a1, b1);
  plswap(a2, b2);
  u32x4 w = {a1, a2, b1, b2};
  return __builtin_bit_cast(b16x8, w);
}

#define AS1 __attribute__((address_space(1)))
#define AS3 __attribute__((address_space(3)))
__device__ __forceinline__ void gload_lds16(const void* g, void* l) {
  __builtin_amdgcn_global_load_lds((const AS1 void*)g, (AS3 void*)l, 16, 0, 0);
}

#define WAITV4() asm volatile("s_waitcnt vmcnt(4)" ::: "memory")
#define WAITV0() asm volatile("s_waitcnt vmcnt(0)" ::: "memory")
#define LGKM0()  asm volatile("s_waitcnt lgkmcnt(0)" ::: "memory")
#define BARRIER() asm volatile("s_barrier" ::: "memory")

// Global pre-swizzle convention: within each 64-elem chunk of a row, 16B slot
// s holds data of slot s ^ (row & 7). global_load_lds (linear) reproduces the
// swizzled LDS layout; ds_read applies idx ^= (row&7)<<3.

// ---------------------------------------------------------------------------
// convert: fp32 weights [1024][1024] -> bf16 pre-swizzled. grid (512, 4).
// ---------------------------------------------------------------------------
__global__ __launch_bounds__(256) void convert_kernel(
    const float* __restrict__ Wq, const float* __restrict__ Wk,
    const float* __restrict__ Wv, const float* __restrict__ Wo,
    unsigned short* __restrict__ wqb, unsigned short* __restrict__ wkb,
    unsigned short* __restrict__ wvb, unsigned short* __restrict__ wob) {
  const float* src; unsigned short* dst;
  switch (blockIdx.y) {
    case 0: src = Wq; dst = wqb; break;
    case 1: src = Wk; dst = wkb; break;
    case 2: src = Wv; dst = wvb; break;
    default: src = Wo; dst = wob; break;
  }
  const int row = blockIdx.x * 2 + (threadIdx.x >> 7);
  const int t = threadIdx.x & 127;
  const float* sp = src + (size_t)row * 1024 + t * 8;
  float4 f0 = *(const float4*)sp;
  float4 f1 = *(const float4*)(sp + 4);
  u16x8 h = { f2b(f0.x), f2b(f0.y), f2b(f0.z), f2b(f0.w),
              f2b(f1.x), f2b(f1.y), f2b(f1.z), f2b(f1.w) };
  const int swcol = ((t >> 3) << 6) | (((t & 7) ^ (row & 7)) << 3);
  *(u16x8*)(dst + (size_t)row * 1024 + swcol) = h;
}

// ---------------------------------------------------------------------------
// Fragment compute + epilogue shared by both GEMM bodies.
// ---------------------------------------------------------------------------
template <int MODE, typename TOUT>
__device__ __forceinline__ void gemm_compute_step(const unsigned short* sA,
                                                  const unsigned short* sB,
                                                  f32x4 (&acc)[2][4],
                                                  int wm, int wn, int lr, int lg) {
  b16x8 af[2][2], bf[4][2];
#pragma unroll
  for (int mb = 0; mb < 2; ++mb)
#pragma unroll
    for (int kh = 0; kh < 2; ++kh) {
      const int r = wm * 32 + mb * 16 + lr;
      af[mb][kh] = as_b(*(const u16x8*)(&sA[(r * 64 + kh * 32 + lg * 8) ^ ((r & 7) << 3)]));
    }
#pragma unroll
  for (int nb = 0; nb < 4; ++nb)
#pragma unroll
    for (int kh = 0; kh < 2; ++kh) {
      const int r = wn * 64 + nb * 16 + lr;
      bf[nb][kh] = as_b(*(const u16x8*)(&sB[(r * 64 + kh * 32 + lg * 8) ^ ((r & 7) << 3)]));
    }
#pragma unroll
  for (int mb = 0; mb < 2; ++mb)
#pragma unroll
    for (int nb = 0; nb < 4; ++nb) {
      acc[mb][nb] = __builtin_amdgcn_mfma_f32_16x16x32_bf16(af[mb][0], bf[nb][0], acc[mb][nb], 0, 0, 0);
      acc[mb][nb] = __builtin_amdgcn_mfma_f32_16x16x32_bf16(af[mb][1], bf[nb][1], acc[mb][nb], 0, 0, 0);
    }
}

template <int MODE, typename TOUT>
__device__ __forceinline__ void gemm_epilogue(f32x4 (&acc)[2][4],
                                              const float* __restrict__ bias,
                                              TOUT* __restrict__ C,
                                              int bm, int bn, int wm, int wn,
                                              int lr, int lg) {
  const float qscale = 0.125f * 1.44269504f;
#pragma unroll
  for (int mb = 0; mb < 2; ++mb)
#pragma unroll
    for (int nb = 0; nb < 4; ++nb) {
      const int c = bn + wn * 64 + nb * 16 + lr;
      const float bv = bias[c];
      const int r0 = bm + wm * 32 + mb * 16 + lg * 4;
      if constexpr (MODE == 2) {
        const int hh = c >> 6, hd = c & 63;
        const int bb = r0 >> 11, t0 = r0 & 2047;
        u16x4 pk = { f2b(acc[mb][nb][0] + bv), f2b(acc[mb][nb][1] + bv),
                     f2b(acc[mb][nb][2] + bv), f2b(acc[mb][nb][3] + bv) };
        const int tsw = (t0 & ~63) | (((((t0 >> 3) & 7) ^ (hd & 7)) << 3)) | (t0 & 7);
        *(u16x4*)(&C[(((size_t)bb * 16 + hh) * 64 + hd) * 2048 + tsw]) = pk;
      } else {
#pragma unroll
        for (int i = 0; i < 4; ++i) {
          float val = acc[mb][nb][i] + bv;
          if constexpr (MODE == 1) val *= qscale;
          if constexpr (MODE == 3) {
            C[(size_t)(r0 + i) * 1024 + c] = val;
          } else {
            const int cc = (c & ~63) | (((((c >> 3) & 7) ^ ((r0 + i) & 7)) << 3)) | (c & 7);
            C[(size_t)(r0 + i) * 1024 + cc] = (TOUT)f2b(val);
          }
        }
      }
    }
}

// ---------------------------------------------------------------------------
// proj GEMM, fp32 A fused convert, PIPELINED (T14): A(k+64) prefetched into
// registers one k-step early; counted vmcnt keeps the prefetch in flight
// across the barrier. Per-step exposed latency = B drain only (as round-12).
// ---------------------------------------------------------------------------
template <int MODE>
__device__ __forceinline__ void gemm_f32A(unsigned short* sA, unsigned short* sB,
                                          const float* __restrict__ A,
                                          const unsigned short* __restrict__ Bm,
                                          const float* __restrict__ bias,
                                          unsigned short* __restrict__ C,
                                          int bm, int bn) {
  const int tid = threadIdx.x;
  const int l = tid & 63, w = tid >> 6;
  const int wm = w >> 1, wn = w & 1;
  const int lr = l & 15, lg = l >> 4;
  const int r8 = l >> 3, sl = l & 7;
  const int arow = tid >> 2, aseg = (tid & 3) * 16;
  const int awr0 = (arow * 64 + aseg) ^ ((arow & 7) << 3);
  const int awr1 = (arow * 64 + aseg + 8) ^ ((arow & 7) << 3);
  const float* arp = A + (size_t)(bm + arow) * 1024 + aseg;

  f32x4 acc[2][4] = {};
  float4 f0, f1, f2, f3;
  f0 = *(const float4*)(arp);      f1 = *(const float4*)(arp + 4);
  f2 = *(const float4*)(arp + 8);  f3 = *(const float4*)(arp + 12);

#pragma unroll 1
  for (int k0 = 0; k0 < 1024; k0 += 64) {
    // issue B stage (4 gload_lds, fire-and-forget until the second wait)
#pragma unroll
    for (int i = 0; i < 4; ++i) {
      const int row = i * 32 + w * 8 + r8;
      gload_lds16(Bm + (size_t)(bn + row) * 1024 + k0 + sl * 8, &sB[i * 2048 + w * 512]);
    }
    WAITV4();   // A-prefetch (4 oldest vmem) complete; B still in flight
    u32x4 h0 = { cvtpk(f0.x, f0.y), cvtpk(f0.z, f0.w),
                 cvtpk(f1.x, f1.y), cvtpk(f1.z, f1.w) };
    u32x4 h1 = { cvtpk(f2.x, f2.y), cvtpk(f2.z, f2.w),
                 cvtpk(f3.x, f3.y), cvtpk(f3.z, f3.w) };
    *(u32x4*)(&sA[awr0]) = h0;
    *(u32x4*)(&sA[awr1]) = h1;
    if (k0 + 64 < 1024) {
      // prefetch next A tile; stays in flight across the barrier + compute
      const float* ap = arp + k0 + 64;
      f0 = *(const float4*)(ap);      f1 = *(const float4*)(ap + 4);
      f2 = *(const float4*)(ap + 8);  f3 = *(const float4*)(ap + 12);
      WAITV4();  // B (oldest 4) complete; new A-prefetch still in flight
    } else {
      WAITV0();  // last step: drain everything
    }
    LGKM0();     // own ds_writes committed
    BARRIER();
    gemm_compute_step<MODE, unsigned short>(sA, sB, acc, wm, wn, lr, lg);
    BARRIER();
  }
  gemm_epilogue<MODE, unsigned short>(acc, bias, C, bm, bn, wm, wn, lr, lg);
}

// bf16-A GEMM (out_kernel): round-12 path, gload_lds both operands.
template <int MODE, typename TOUT>
__device__ __forceinline__ void gemm_b16A(unsigned short* sA, unsigned short* sB,
                                          const unsigned short* __restrict__ A,
                                          const unsigned short* __restrict__ Bm,
                                          const float* __restrict__ bias,
                                          TOUT* __restrict__ C,
                                          int bm, int bn) {
  const int tid = threadIdx.x;
  const int l = tid & 63, w = tid >> 6;
  const int wm = w >> 1, wn = w & 1;
  const int lr = l & 15, lg = l >> 4;
  const int r8 = l >> 3, sl = l & 7;

  f32x4 acc[2][4] = {};

  for (int k0 = 0; k0 < 1024; k0 += 64) {
#pragma unroll
    for (int i = 0; i < 2; ++i) {
      gload_lds16(A + (size_t)(bm + i * 32 + w * 8 + r8) * 1024 + k0 + sl * 8,
                  &sA[i * 2048 + w * 512]);
    }
#pragma unroll
    for (int i = 0; i < 4; ++i) {
      const int row = i * 32 + w * 8 + r8;
      gload_lds16(Bm + (size_t)(bn + row) * 1024 + k0 + sl * 8, &sB[i * 2048 + w * 512]);
    }
    __syncthreads();
    gemm_compute_step<MODE, TOUT>(sA, sB, acc, wm, wn, lr, lg);
    __syncthreads();
  }
  gemm_epilogue<MODE, TOUT>(acc, bias, C, bm, bn, wm, wn, lr, lg);
}

// flat grid 1536 = g*64 + bx*8 + p, panel = g*8 + p: the 8 bx-siblings of an
// A-panel are temporally adjacent AND same id%8 (same XCD) -> panel L2-hot.
__global__ __launch_bounds__(256) void proj_kernel(
    const float* __restrict__ q, const float* __restrict__ k, const float* __restrict__ v,
    const unsigned short* __restrict__ wqb, const float* __restrict__ bq,
    const unsigned short* __restrict__ wkb, const float* __restrict__ bk,
    const unsigned short* __restrict__ wvb, const float* __restrict__ bv,
    unsigned short* __restrict__ Qh, unsigned short* __restrict__ Kh,
    unsigned short* __restrict__ Vt) {
  __shared__ __align__(16) unsigned short sA[64 * 64];
  __shared__ __align__(16) unsigned short sB[128 * 64];
  const int id = blockIdx.x;
  const int g = id >> 6, r = id & 63;
  const int bn = (r >> 3) * 128;
  const int panel = g * 8 + (r & 7);
  const int bz = panel >> 6;
  const int bm = (panel & 63) * 64;
  if (bz == 0)      gemm_f32A<1>(sA, sB, q, wqb, bq, Qh, bm, bn);
  else if (bz == 1) gemm_f32A<0>(sA, sB, k, wkb, bk, Kh, bm, bn);
  else              gemm_f32A<2>(sA, sB, v, wvb, bv, Vt, bm, bn);
}

// flat grid 512 = g*64 + bx*8 + p, panel(by) = g*8 + p. Same sibling locality.
__global__ __launch_bounds__(256) void out_kernel(
    const unsigned short* __restrict__ X, const unsigned short* __restrict__ wob,
    const float* __restrict__ bo, float* __restrict__ out) {
  __shared__ __align__(16) unsigned short sA[64 * 64];
  __shared__ __align__(16) unsigned short sB[128 * 64];
  const int id = blockIdx.x;
  const int g = id >> 6, r = id & 63;
  const int bn = (r >> 3) * 128;
  const int bm = (g * 8 + (r & 7)) * 64;
  gemm_b16A<3, float>(sA, sB, X, wob, bo, out, bm, bn);
}

// ---------------------------------------------------------------------------
// Flash attention — round-8 body (53.5 µs, VGPR 64, no spill), unchanged.
// The defer-max `if (__any)` branch is LOAD-BEARING for register allocation
// (rounds 10-11: removing it caused 143 MB scratch traffic).
// ---------------------------------------------------------------------------
__global__ __launch_bounds__(512, 4) void attn_kernel(
    const unsigned short* __restrict__ Qh, const unsigned short* __restrict__ Kh,
    const unsigned short* __restrict__ Vt, unsigned short* __restrict__ X) {
  __shared__ __align__(16) unsigned short sMem[8][4096];   // 64 KB

  const int tid = threadIdx.x;
  const int l = tid & 63, wq = tid >> 6;
  const int half = wq >> 2, w4 = wq & 3;
  const int lq = l & 31, lg = l >> 5;

  // XCD-aware bijective swizzle (512 blocks = 8 XCD x 64).
  const int id = blockIdx.x + (int)(gridDim.x * blockIdx.y);
  const int id2 = (id & 7) * 64 + (id >> 3);
  const int bx = id2 & 15, by = id2 >> 4;
  const int b = by >> 4, h = by & 15;
  const int q0 = bx * 128 + w4 * 32;
  const int kvbase = half * 1024;

  const size_t baseQK = (size_t)b * 2048 * 1024 + (size_t)h * 64;
  const size_t baseV  = ((size_t)(b * 16 + h)) * 64 * 2048;

  unsigned short* sK0 = &sMem[half * 4 + 0][0];
  unsigned short* sK1 = &sMem[half * 4 + 1][0];
  unsigned short* sV0 = &sMem[half * 4 + 2][0];
  unsigned short* sV1 = &sMem[half * 4 + 3][0];

  const int rk = lq & 7;
  b16x8 qf0, qf1, qf2, qf3;
  {
    const unsigned short* qp = Qh + baseQK + (size_t)(q0 + lq) * 1024;
    qf0 = as_b(*(const u16x8*)(qp + (((0 + lg) ^ rk) << 3)));
    qf1 = as_b(*(const u16x8*)(qp + (((2 + lg) ^ rk) << 3)));
    qf2 = as_b(*(const u16x8*)(qp + (((4 + lg) ^ rk) << 3)));
    qf3 = as_b(*(const u16x8*)(qp + (((6 + lg) ^ rk) << 3)));
  }

  const int r8 = l >> 3, sl = l & 7;

  auto stageKV = [&](unsigned short* dK, unsigned short* dV, int kv0) {
#pragma unroll
    for (int i = 0; i < 2; ++i) {
      const int rowb = 16 * w4 + 8 * i;
      gload_lds16(Kh + baseQK + (size_t)(kv0 + rowb + r8) * 1024 + sl * 8, dK + rowb * 64);
      gload_lds16(Vt + baseV + (size_t)(rowb + r8) * 2048 + kv0 + sl * 8, dV + rowb * 64);
    }
  };

  float m_run = 0.f, l_run = 0.f;   // m relative; defer-max keeps it stale
  f32x16 Oa = {}, Ob = {};
  const int sw = (lq & 7) << 3;

  auto body = [&](const unsigned short* K_, const unsigned short* V_) {
    // S = QK^T - m_run  (fold the softmax shift into the MFMA C-init)
    f32x16 s0, s1;
#pragma unroll
    for (int j = 0; j < 16; ++j) { s0[j] = -m_run; s1[j] = -m_run; }
    __builtin_amdgcn_s_setprio(1);
#pragma unroll
    for (int c = 0; c < 4; ++c) {
      const int hd8 = c * 16 + 8 * lg;
      b16x8 kf0 = as_b(*(const u16x8*)(&K_[lq * 64 + (hd8 ^ sw)]));
      b16x8 kf1 = as_b(*(const u16x8*)(&K_[(32 + lq) * 64 + (hd8 ^ sw)]));
      b16x8 qf = (c == 0) ? qf0 : (c == 1) ? qf1 : (c == 2) ? qf2 : qf3;
      s0 = __builtin_amdgcn_mfma_f32_32x32x16_bf16(kf0, qf, s0, 0, 0, 0);
      s1 = __builtin_amdgcn_mfma_f32_32x32x16_bf16(kf1, qf, s1, 0, 0, 0);
    }
    __builtin_amdgcn_s_setprio(0);

    // tree max of (score - m_run)
    float a0 = fmaxf(fmaxf(s0[0], s0[1]), fmaxf(s0[2], s0[3]));
    float a1 = fmaxf(fmaxf(s0[4], s0[5]), fmaxf(s0[6], s0[7]));
    float a2 = fmaxf(fmaxf(s0[8], s0[9]), fmaxf(s0[10], s0[11]));
    float a3 = fmaxf(fmaxf(s0[12], s0[13]), fmaxf(s0[14], s0[15]));
    float a4 = fmaxf(fmaxf(s1[0], s1[1]), fmaxf(s1[2], s1[3]));
    float a5 = fmaxf(fmaxf(s1[4], s1[5]), fmaxf(s1[6], s1[7]));
    float a6 = fmaxf(fmaxf(s1[8], s1[9]), fmaxf(s1[10], s1[11]));
    float a7 = fmaxf(fmaxf(s1[12], s1[13]), fmaxf(s1[14], s1[15]));
    float mx = fmaxf(fmaxf(fmaxf(a0, a1), fmaxf(a2, a3)),
                     fmaxf(fmaxf(a4, a5), fmaxf(a6, a7)));
    mx = fmaxf(mx, __shfl_xor(mx, 32));

    // defer-max: only rescale when the shifted max exceeds 8 (exp2 domain)
    if (__any(mx > 8.0f)) {
      const float dm = fmaxf(mx, 0.f);
      const float al = fexp2(-dm);
      m_run += dm;
      l_run *= al;
#pragma unroll
      for (int j = 0; j < 16; ++j) {
        Oa[j] *= al; Ob[j] *= al; s0[j] -= dm; s1[j] -= dm;
      }
    }

#pragma unroll
    for (int j = 0; j < 16; ++j) s0[j] = fexp2(s0[j]);
#pragma unroll
    for (int j = 0; j < 16; ++j) s1[j] = fexp2(s1[j]);

    float r0 = ((s0[0] + s0[1]) + (s0[2] + s0[3])) + ((s0[4] + s0[5]) + (s0[6] + s0[7]));
    float r1 = ((s0[8] + s0[9]) + (s0[10] + s0[11])) + ((s0[12] + s0[13]) + (s0[14] + s0[15]));
    float r2 = ((s1[0] + s1[1]) + (s1[2] + s1[3])) + ((s1[4] + s1[5]) + (s1[6] + s1[7]));
    float r3 = ((s1[8] + s1[9]) + (s1[10] + s1[11])) + ((s1[12] + s1[13]) + (s1[14] + s1[15]));
    float rs = (r0 + r1) + (r2 + r3);
    rs += __shfl_xor(rs, 32);
    l_run += rs;

    b16x8 pb0 = mkchunk(s0[0], s0[1], s0[2], s0[3], s0[4], s0[5], s0[6], s0[7]);
    b16x8 pb1 = mkchunk(s0[8], s0[9], s0[10], s0[11], s0[12], s0[13], s0[14], s0[15]);
    b16x8 pb2 = mkchunk(s1[0], s1[1], s1[2], s1[3], s1[4], s1[5], s1[6], s1[7]);
    b16x8 pb3 = mkchunk(s1[8], s1[9], s1[10], s1[11], s1[12], s1[13], s1[14], s1[15]);

    __builtin_amdgcn_s_setprio(1);
#pragma unroll
    for (int c = 0; c < 4; ++c) {
      const int kv8 = c * 16 + 8 * lg;
      b16x8 vfa = as_b(*(const u16x8*)(&V_[lq * 64 + (kv8 ^ sw)]));
      b16x8 vfb = as_b(*(const u16x8*)(&V_[(32 + lq) * 64 + (kv8 ^ sw)]));
      b16x8 pb = (c == 0) ? pb0 : (c == 1) ? pb1 : (c == 2) ? pb2 : pb3;
      Oa = __builtin_amdgcn_mfma_f32_32x32x16_bf16(vfa, pb, Oa, 0, 0, 0);
      Ob = __builtin_amdgcn_mfma_f32_32x32x16_bf16(vfb, pb, Ob, 0, 0, 0);
    }
    __builtin_amdgcn_s_setprio(0);
  };

  // prologue: two tiles in flight
  stageKV(sK0, sV0, kvbase);
  stageKV(sK1, sV1, kvbase + 64);

#pragma unroll 1
  for (int tt = 0; tt < 16; tt += 2) {
    WAITV4();
    BARRIER();
    body(sK0, sV0);
    LGKM0();
    BARRIER();
    if (tt + 2 < 16) stageKV(sK0, sV0, kvbase + (tt + 2) * 64);

    if (tt + 3 < 16) { WAITV4(); } else { WAITV0(); }
    BARRIER();
    body(sK1, sV1);
    LGKM0();
    BARRIER();
    if (tt + 3 < 16) stageKV(sK1, sV1, kvbase + (tt + 3) * 64);
  }

  // merge the two kv-halves (LSE combine), then write X
  float* fb = (float*)&sMem[0][0];   // 34 x 256 floats, reuses K/V space
  const int mbase = w4 * 64 + l;
  if (half == 1) {
    fb[0 * 256 + mbase] = m_run;
    fb[1 * 256 + mbase] = l_run;
#pragma unroll
    for (int j = 0; j < 16; ++j) fb[(2 + j) * 256 + mbase] = Oa[j];
#pragma unroll
    for (int j = 0; j < 16; ++j) fb[(18 + j) * 256 + mbase] = Ob[j];
  }
  __syncthreads();
  if (half == 0) {
    const float m2 = fb[0 * 256 + mbase], l2 = fb[1 * 256 + mbase];
    const float mM = fmaxf(m_run, m2);
    const float c1 = fexp2(m_run - mM), c2 = fexp2(m2 - mM);
    const float inv = 1.0f / (l_run * c1 + l2 * c2);
    const float ia = c1 * inv, ib = c2 * inv;
#pragma unroll
    for (int j = 0; j < 16; ++j) {
      Oa[j] = Oa[j] * ia + fb[(2 + j) * 256 + mbase] * ib;
      Ob[j] = Ob[j] * ia + fb[(18 + j) * 256 + mbase] * ib;
    }
    unsigned short* xp = X + baseQK + (size_t)(q0 + lq) * 1024;
#pragma unroll
    for (int g = 0; g < 4; ++g) {
      u32x2 wa = { cvtpk(Oa[4 * g + 0], Oa[4 * g + 1]),
                   cvtpk(Oa[4 * g + 2], Oa[4 * g + 3]) };
      *(u32x2*)(xp + ((g ^ rk) << 3) + 4 * lg) = wa;
      u32x2 wb = { cvtpk(Ob[4 * g + 0], Ob[4 * g + 1]),
                   cvtpk(Ob[4 * g + 2], Ob[4 * g + 3]) };
      *(u32x2*)(xp + (((4 + g) ^ rk) << 3) + 4 * lg) = wb;
    }
  }
}

extern "C" void kernel_launch(void* const* d_in, const int* in_sizes, int n_in,
                              void* d_out, int out_size, void* d_ws, size_t ws_size,
                              hipStream_t stream) {
  const float* q  = (const float*)d_in[0];
  const float* k  = (const float*)d_in[1];
  const float* v  = (const float*)d_in[2];
  const float* Wq = (const float*)d_in[3];
  const float* bq = (const float*)d_in[4];
  const float* Wk = (const float*)d_in[5];
  const float* bk = (const float*)d_in[6];
  const float* Wv = (const float*)d_in[7];
  const float* bv = (const float*)d_in[8];
  const float* Wo = (const float*)d_in[9];
  const float* bo = (const float*)d_in[10];

  unsigned short* ws = (unsigned short*)d_ws;
  const size_t M1 = (size_t)1024 * 1024;
  unsigned short* wqb = ws + 12 * M1;
  unsigned short* wkb = ws + 13 * M1;
  unsigned short* wvb = ws + 14 * M1;
  unsigned short* wob = ws + 15 * M1;
  unsigned short* Qh  = ws + 16 * M1;
  unsigned short* Kh  = ws + 20 * M1;
  unsigned short* Vt  = ws + 24 * M1;
  unsigned short* X   = ws;              // first 4M elems

  dim3 blk(256);
  convert_kernel<<<dim3(512, 4), blk, 0, stream>>>(Wq, Wk, Wv, Wo, wqb, wkb, wvb, wob);
  proj_kernel<<<dim3(1536), blk, 0, stream>>>(q, k, v, wqb, bq, wkb, bk, wvb, bv,
                                              Qh, Kh, Vt);
  attn_kernel<<<dim3(16, 32), dim3(512), 0, stream>>>(Qh, Kh, Vt, X);
  out_kernel<<<dim3(512), blk, 0, stream>>>(X, wob, bo, (float*)d_out);
}